// Round 5
// baseline (178.354 us; speedup 1.0000x reference)
//
#include <hip/hip_runtime.h>
#include <hip/hip_bf16.h>

// NT-Xent (SimCLR) loss, B=4096, D=256, N=8192, T=0.5.
// loss = [ sum_i log(sum_{j!=i} exp(sim_ij * 2)) - 4 * sum_{i<B} pos_i ] / N
// sim symmetric => row sums computed as column sums of MFMA tiles (per-lane).
//
// Z pre-scaled by sqrt(2*log2 e) so MFMA emits sim*2*log2e (epilogue = bare
// exp2); pos uses the exact fp32 path. GEMM: global_load_lds (16B) staging
// with the XOR bank-swizzle folded into the SOURCE address (LDS dst must be
// wave-uniform base + lane*16), double-buffered LDS, ONE barrier per tile.
// Grid 1024 = 4 blocks/CU so independent blocks interleave MFMA bursts
// against each other's exp/staging phases (R4 lesson: 2 blocks/CU left the
// matrix pipe idle 2/3 of the time; MfmaUtil*dur matched the 13.7us floor).

constexpr int BB = 4096;     // batch
constexpr int NN = 8192;     // 2*batch
constexpr int DD = 256;      // feature dim
constexpr int RT = 256;      // r-rows per block
constexpr int CC = 256;      // c-columns per block chunk
constexpr int NRT = NN / RT; // 32 row tiles
constexpr int NCH = NN / CC; // 32 column chunks
constexpr int CSTEPS = CC / 32;

typedef _Float16 half4v __attribute__((ext_vector_type(4)));
typedef _Float16 half8v __attribute__((ext_vector_type(8)));
typedef float floatx16 __attribute__((ext_vector_type(16)));

// sqrt(2*log2(e)) : each side of the dot product carries one factor.
#define SQK 1.69864414f

// ---------------- Kernel 1: normalize rows -> f16 (pre-scaled), pos, zero ----
__global__ __launch_bounds__(256) void nt_normalize(
    const float* __restrict__ zi, const float* __restrict__ zj,
    _Float16* __restrict__ Z, float* __restrict__ posPartial,
    float* __restrict__ rowsum)
{
    const int lane = threadIdx.x & 63;
    const int wave = threadIdx.x >> 6;
    const int i = blockIdx.x * 4 + wave;   // pair index, < BB

    // Zero rowsum (8192 floats); stream-ordered before simexp, so no race.
    if (blockIdx.x < 32) rowsum[blockIdx.x * 256 + threadIdx.x] = 0.f;

    const float4 a = ((const float4*)(zi + (size_t)i * DD))[lane];
    const float4 b = ((const float4*)(zj + (size_t)i * DD))[lane];

    float ssi = a.x*a.x + a.y*a.y + a.z*a.z + a.w*a.w;
    float ssj = b.x*b.x + b.y*b.y + b.z*b.z + b.w*b.w;
    float dd  = a.x*b.x + a.y*b.y + a.z*b.z + a.w*b.w;
#pragma unroll
    for (int off = 32; off > 0; off >>= 1) {
        ssi += __shfl_xor(ssi, off);
        ssj += __shfl_xor(ssj, off);
        dd  += __shfl_xor(dd,  off);
    }
    const float invi = rsqrtf(ssi) * SQK;   // fold sqrt(2*log2e) into each side
    const float invj = rsqrtf(ssj) * SQK;

    half4v ha, hb;
    ha.x = (_Float16)(a.x * invi); ha.y = (_Float16)(a.y * invi);
    ha.z = (_Float16)(a.z * invi); ha.w = (_Float16)(a.w * invi);
    hb.x = (_Float16)(b.x * invj); hb.y = (_Float16)(b.y * invj);
    hb.z = (_Float16)(b.z * invj); hb.w = (_Float16)(b.w * invj);

    ((half4v*)(Z + (size_t)i * DD))[lane]        = ha;
    ((half4v*)(Z + (size_t)(BB + i) * DD))[lane] = hb;

    __shared__ float ps[4];
    if (lane == 0) ps[wave] = dd * invi * invj * (1.0f / (SQK * SQK)); // exact pos
    __syncthreads();
    if (threadIdx.x == 0)
        posPartial[blockIdx.x] = ps[0] + ps[1] + ps[2] + ps[3];
}

// ---------------- Kernel 2: fused sim-GEMM + exp + row-sum -------------------
// Grid: NRT * NCH = 1024 blocks (4/CU), 256 threads (4 waves). Each wave owns
// 64 r-rows (2 B-fragment sets in registers for whole K=256). c-tiles of 32
// rows staged via global_load_lds into double-buffered swizzled LDS; one
// barrier per tile (waves read lds[cs&1], hardware writes lds[(cs+1)&1]).
__global__ __launch_bounds__(256, 4) void nt_simexp(
    const _Float16* __restrict__ Z, float* __restrict__ rowsum)
{
    __shared__ _Float16 lds[2][32 * DD];   // 2 x 16 KB, swizzled at the source

    const int bid = blockIdx.x;
    const int rt = bid & (NRT - 1);
    const int ch = bid >> 5;            // NRT == 32
    const int tid = threadIdx.x;
    const int wave = tid >> 6;
    const int lane = tid & 63;
    const int lm = lane & 31;           // MFMA row/col index within 32
    const int lh = lane >> 5;           // half select

    const int rbase = rt * RT + wave * 64;  // this wave's 64 r-rows
    const int cchunk = ch * CC;

    // Stage one 32x256 c-tile into lds[buf] with global_load_lds.
    // Lane handles granule gi = (it*4 + wave)*64 + lane: c = gi>>5, phys = gi&31;
    // source granule = phys ^ (c&7) (swizzle folded into the source address;
    // LDS destination is wave-uniform base + lane*16 as HW requires).
    auto stageTile = [&](int cs, int buf) {
#pragma unroll
        for (int it = 0; it < 4; ++it) {
            const int gi = (it * 4 + wave) * 64 + lane;
            const int c = gi >> 5;
            const int phys = gi & 31;
            const _Float16* src =
                Z + (size_t)(cchunk + cs * 32 + c) * DD + ((phys ^ (c & 7)) * 8);
            __builtin_amdgcn_global_load_lds(
                (const __attribute__((address_space(1))) void*)src,
                (__attribute__((address_space(3))) void*)&lds[buf][(it * 4 + wave) * 64 * 8],
                16, 0, 0);
        }
    };

    // B fragments: lane holds col n = lm, k = lh*8 + j (j=0..7), 16 k-steps.
    half8v bfrag[2][16];
#pragma unroll
    for (int b = 0; b < 2; ++b) {
        const _Float16* rowp = Z + (size_t)(rbase + b * 32 + lm) * DD + lh * 8;
#pragma unroll
        for (int s = 0; s < 16; ++s)
            bfrag[b][s] = *(const half8v*)(rowp + s * 16);
    }

    float ea0 = 0.f, ea1 = 0.f, eb0 = 0.f, eb1 = 0.f;
    const bool blockdiag = (ch == rt);

    stageTile(0, 0);

    for (int cs = 0; cs < CSTEPS; ++cs) {
        const int cbase = cchunk + cs * 32;

        __syncthreads();                          // lds[cs&1] ready
        if (cs + 1 < CSTEPS) stageTile(cs + 1, (cs + 1) & 1);  // DMA other buf

        floatx16 c0, c1;
#pragma unroll
        for (int r = 0; r < 16; ++r) { c0[r] = 0.f; c1[r] = 0.f; }

        const _Float16* abuf = lds[cs & 1];
#pragma unroll
        for (int s = 0; s < 16; ++s) {
            // A fragment: lane = row lm, k = lh*8 + j; logical granule 2s+lh.
            const int phys = (2 * s + lh) ^ (lm & 7);
            half8v af = *(const half8v*)(&abuf[lm * DD + phys * 8]);
            c0 = __builtin_amdgcn_mfma_f32_32x32x16_f16(af, bfrag[0][s], c0, 0, 0, 0);
            c1 = __builtin_amdgcn_mfma_f32_32x32x16_f16(af, bfrag[1][s], c1, 0, 0, 0);
        }

        // Epilogue: sims arrive pre-scaled by 2*log2e -> bare exp2.
        const bool m0 = blockdiag && (cbase == rbase);
        const bool m1 = blockdiag && (cbase == rbase + 32);
        if (!(m0 | m1)) {
#pragma unroll
            for (int r = 0; r < 16; r += 2) {
                ea0 += __builtin_amdgcn_exp2f(c0[r]);
                eb0 += __builtin_amdgcn_exp2f(c0[r + 1]);
                ea1 += __builtin_amdgcn_exp2f(c1[r]);
                eb1 += __builtin_amdgcn_exp2f(c1[r + 1]);
            }
        } else {
#pragma unroll
            for (int r = 0; r < 16; ++r) {
                const int mrow = (r & 3) + 8 * (r >> 2) + 4 * lh; // MFMA C row
                float e0 = __builtin_amdgcn_exp2f(c0[r]);
                float e1 = __builtin_amdgcn_exp2f(c1[r]);
                if (m0 && (mrow == lm)) e0 = 0.f;
                if (m1 && (mrow == lm)) e1 = 0.f;
                if (r & 1) { eb0 += e0; eb1 += e1; }
                else       { ea0 += e0; ea1 += e1; }
            }
        }
    }

    ea0 += eb0; ea1 += eb1;
    // Column (== row, symmetry) totals: combine the two lane-halves.
    ea0 += __shfl_xor(ea0, 32);
    ea1 += __shfl_xor(ea1, 32);
    if (lane < 32) {
        atomicAdd(&rowsum[rbase + lm], ea0);
        atomicAdd(&rowsum[rbase + 32 + lm], ea1);
    }
}

// ---------------- Kernel 3: finalize ----------------------------------------
__global__ __launch_bounds__(256) void nt_finalize(
    const float* __restrict__ rowsum, const float* __restrict__ posPartial,
    float* __restrict__ out)
{
    const int tid = threadIdx.x;
    float acc = 0.f;
#pragma unroll
    for (int it = 0; it < NN / 256; ++it)
        acc += __builtin_amdgcn_logf(rowsum[tid + it * 256]);   // log2
    float pacc = 0.f;
#pragma unroll
    for (int it = 0; it < 4; ++it)
        pacc += posPartial[tid + it * 256];

#pragma unroll
    for (int off = 32; off > 0; off >>= 1) {
        acc  += __shfl_xor(acc,  off);
        pacc += __shfl_xor(pacc, off);
    }
    __shared__ float sa[4], sp[4];
    const int wave = tid >> 6;
    if ((tid & 63) == 0) { sa[wave] = acc; sp[wave] = pacc; }
    __syncthreads();
    if (tid == 0) {
        const float lntot = (sa[0] + sa[1] + sa[2] + sa[3]) * 0.6931471805599453f;
        const float ptot  = sp[0] + sp[1] + sp[2] + sp[3];
        out[0] = (lntot - 4.0f * ptot) * (1.0f / (float)NN);
    }
}

// ---------------- Launch ------------------------------------------------------
extern "C" void kernel_launch(void* const* d_in, const int* in_sizes, int n_in,
                              void* d_out, int out_size, void* d_ws, size_t ws_size,
                              hipStream_t stream) {
    const float* zi = (const float*)d_in[0];
    const float* zj = (const float*)d_in[1];
    float* out = (float*)d_out;

    _Float16* Z = (_Float16*)d_ws;                                  // 4 MB
    float* rowsum = (float*)((char*)d_ws + (size_t)NN * DD * 2);    // 32 KB
    float* posPartial = rowsum + NN;                                // 4 KB

    nt_normalize<<<BB / 4, 256, 0, stream>>>(zi, zj, Z, posPartial, rowsum);
    nt_simexp<<<NRT * NCH, 256, 0, stream>>>((const _Float16*)Z, rowsum);
    nt_finalize<<<1, 256, 0, stream>>>(rowsum, posPartial, out);
}

// Round 6
// 110.573 us; speedup vs baseline: 1.6130x; 1.6130x over previous
//
#include <hip/hip_runtime.h>
#include <hip/hip_bf16.h>

// NT-Xent (SimCLR) loss, B=4096, D=256, N=8192, T=0.5.
// loss = [ sum_i log(sum_{j!=i} exp(sim_ij * 2)) - 4 * sum_{i<B} pos_i ] / N
// sim symmetric => row sums computed as column sums of MFMA tiles (per-lane).
//
// Z pre-scaled by sqrt(2*log2 e) so MFMA emits sim*2*log2e (epilogue = bare
// exp2); pos uses the exact fp32 path.
//
// R5 lesson (VGPR_Count=64, FETCH 345MB): launch_bounds(256,4) demoted bfrag
// to per-tile global re-loads -> L2/L3 storm. bfrag residency is everything:
// stay at (256,2) / ~225 VGPRs.
// This round: cross-tile software pipeline (legal because c-tiles are
// independent -- no K-accumulation): per tile, issue globals, run the
// PREVIOUS tile's exp-epilogue (double accumulators) while they fly and the
// wave's own MFMAs drain, then stage, one barrier, then MFMA into the other
// acc set. Waves hit the barrier with MFMAs still in flight.

constexpr int BB = 4096;     // batch
constexpr int NN = 8192;     // 2*batch
constexpr int DD = 256;      // feature dim
constexpr int RT = 256;      // r-rows per block
constexpr int CC = 512;      // c-columns per block chunk
constexpr int NRT = NN / RT; // 32 row tiles
constexpr int NCH = NN / CC; // 16 column chunks
constexpr int CSTEPS = CC / 32;

typedef _Float16 half4v __attribute__((ext_vector_type(4)));
typedef _Float16 half8v __attribute__((ext_vector_type(8)));
typedef float floatx16 __attribute__((ext_vector_type(16)));

// sqrt(2*log2(e)) : each side of the dot product carries one factor.
#define SQK 1.69864414f

// ---------------- Kernel 1: normalize rows -> f16 (pre-scaled), pos, zero ----
__global__ __launch_bounds__(256) void nt_normalize(
    const float* __restrict__ zi, const float* __restrict__ zj,
    _Float16* __restrict__ Z, float* __restrict__ posPartial,
    float* __restrict__ rowsum)
{
    const int lane = threadIdx.x & 63;
    const int wave = threadIdx.x >> 6;
    const int i = blockIdx.x * 4 + wave;   // pair index, < BB

    // Zero rowsum (8192 floats); stream-ordered before simexp, so no race.
    if (blockIdx.x < 32) rowsum[blockIdx.x * 256 + threadIdx.x] = 0.f;

    const float4 a = ((const float4*)(zi + (size_t)i * DD))[lane];
    const float4 b = ((const float4*)(zj + (size_t)i * DD))[lane];

    float ssi = a.x*a.x + a.y*a.y + a.z*a.z + a.w*a.w;
    float ssj = b.x*b.x + b.y*b.y + b.z*b.z + b.w*b.w;
    float dd  = a.x*b.x + a.y*b.y + a.z*b.z + a.w*b.w;
#pragma unroll
    for (int off = 32; off > 0; off >>= 1) {
        ssi += __shfl_xor(ssi, off);
        ssj += __shfl_xor(ssj, off);
        dd  += __shfl_xor(dd,  off);
    }
    const float invi = rsqrtf(ssi) * SQK;   // fold sqrt(2*log2e) into each side
    const float invj = rsqrtf(ssj) * SQK;

    half4v ha, hb;
    ha.x = (_Float16)(a.x * invi); ha.y = (_Float16)(a.y * invi);
    ha.z = (_Float16)(a.z * invi); ha.w = (_Float16)(a.w * invi);
    hb.x = (_Float16)(b.x * invj); hb.y = (_Float16)(b.y * invj);
    hb.z = (_Float16)(b.z * invj); hb.w = (_Float16)(b.w * invj);

    ((half4v*)(Z + (size_t)i * DD))[lane]        = ha;
    ((half4v*)(Z + (size_t)(BB + i) * DD))[lane] = hb;

    __shared__ float ps[4];
    if (lane == 0) ps[wave] = dd * invi * invj * (1.0f / (SQK * SQK)); // exact pos
    __syncthreads();
    if (threadIdx.x == 0)
        posPartial[blockIdx.x] = ps[0] + ps[1] + ps[2] + ps[3];
}

// ---------------- Kernel 2: fused sim-GEMM + exp + row-sum -------------------
// Grid: NRT * NCH = 512 blocks (2/CU), 256 threads (4 waves). Each wave owns
// 64 r-rows (2 B-fragment sets resident in registers for whole K=256).
// c-tiles of 32 rows staged coalesced into double-buffered swizzled LDS;
// ONE barrier per tile; epilogue of tile cs-1 deferred into tile cs's
// staging window (double accumulators).
__global__ __launch_bounds__(256, 2) void nt_simexp(
    const _Float16* __restrict__ Z, float* __restrict__ rowsum)
{
    __shared__ _Float16 lds[2][32 * DD];   // 2 x 16 KB, 16B-granule swizzled

    const int bid = blockIdx.x;
    const int rt = bid & (NRT - 1);
    const int ch = bid >> 5;            // NRT == 32
    const int tid = threadIdx.x;
    const int wave = tid >> 6;
    const int lane = tid & 63;
    const int lm = lane & 31;           // MFMA row/col index within 32
    const int lh = lane >> 5;           // half select

    const int rbase = rt * RT + wave * 64;  // this wave's 64 r-rows
    const int cchunk = ch * CC;
    const bool blockdiag = (ch == (rt >> 1));

    // B fragments: lane holds col n = lm, k = lh*8 + j (j=0..7), 16 k-steps.
    half8v bfrag[2][16];
#pragma unroll
    for (int b = 0; b < 2; ++b) {
        const _Float16* rowp = Z + (size_t)(rbase + b * 32 + lm) * DD + lh * 8;
#pragma unroll
        for (int s = 0; s < 16; ++s)
            bfrag[b][s] = *(const half8v*)(rowp + s * 16);
    }

    // Staging granule coords (4 granules of 16B per thread per tile).
    const int g_c0 = tid >> 5;          // c row for it=0
    const int g_kc = tid & 31;

    half8v pre[4];
    auto loadTile = [&](int cs) {
#pragma unroll
        for (int it = 0; it < 4; ++it) {
            const int c = g_c0 + it * 8;
            pre[it] = *(const half8v*)(Z + (size_t)(cchunk + cs * 32 + c) * DD + g_kc * 8);
        }
    };
    auto storeTile = [&](int buf) {
#pragma unroll
        for (int it = 0; it < 4; ++it) {
            const int c = g_c0 + it * 8;
            *(half8v*)(&lds[buf][c * DD + (g_kc ^ (c & 7)) * 8]) = pre[it];
        }
    };

    floatx16 a0[2], a1[2];              // double accumulator sets (parity cs&1)
    float ea0 = 0.f, ea1 = 0.f, eb0 = 0.f, eb1 = 0.f;

    // k-loop for tile cs into acc set p.
    auto kloop = [&](int p, int buf) {
#pragma unroll
        for (int r = 0; r < 16; ++r) { a0[p][r] = 0.f; a1[p][r] = 0.f; }
        const _Float16* abuf = lds[buf];
#pragma unroll
        for (int s = 0; s < 16; ++s) {
            // A fragment: lane = row lm, k = lh*8 + j; logical granule 2s+lh.
            const int phys = (2 * s + lh) ^ (lm & 7);
            half8v af = *(const half8v*)(&abuf[lm * DD + phys * 8]);
            a0[p] = __builtin_amdgcn_mfma_f32_32x32x16_f16(af, bfrag[0][s], a0[p], 0, 0, 0);
            a1[p] = __builtin_amdgcn_mfma_f32_32x32x16_f16(af, bfrag[1][s], a1[p], 0, 0, 0);
        }
    };

    // Epilogue for tile cs (acc set p): exp2 (Z pre-scaled), mask diag, reduce.
    auto epilogue = [&](int p, int cs) {
        const int cbase = cchunk + cs * 32;
        const bool m0 = blockdiag && (cbase == rbase);
        const bool m1 = blockdiag && (cbase == rbase + 32);
        if (!(m0 | m1)) {
#pragma unroll
            for (int r = 0; r < 16; r += 2) {
                ea0 += __builtin_amdgcn_exp2f(a0[p][r]);
                eb0 += __builtin_amdgcn_exp2f(a0[p][r + 1]);
                ea1 += __builtin_amdgcn_exp2f(a1[p][r]);
                eb1 += __builtin_amdgcn_exp2f(a1[p][r + 1]);
            }
        } else {
#pragma unroll
            for (int r = 0; r < 16; ++r) {
                const int mrow = (r & 3) + 8 * (r >> 2) + 4 * lh; // MFMA C row
                float e0 = __builtin_amdgcn_exp2f(a0[p][r]);
                float e1 = __builtin_amdgcn_exp2f(a1[p][r]);
                if (m0 && (mrow == lm)) e0 = 0.f;
                if (m1 && (mrow == lm)) e1 = 0.f;
                if (r & 1) { eb0 += e0; eb1 += e1; }
                else       { ea0 += e0; ea1 += e1; }
            }
        }
    };

    // Prologue: tile 0.
    loadTile(0);
    storeTile(0);
    __syncthreads();
    kloop(0, 0);                        // tile 0 MFMAs in flight

    for (int cs = 1; cs < CSTEPS; ++cs) {
        loadTile(cs);                   // issue globals (async)
        epilogue((cs - 1) & 1, cs - 1); // prev tile's exp while loads fly
        storeTile(cs & 1);              // vmcnt wait + ds_write (other buffer)
        __syncthreads();                // one barrier per tile
        kloop(cs & 1, cs & 1);          // new MFMAs; loop back with them in flight
    }
    epilogue((CSTEPS - 1) & 1, CSTEPS - 1);

    ea0 += eb0; ea1 += eb1;
    // Column (== row, symmetry) totals: combine the two lane-halves.
    ea0 += __shfl_xor(ea0, 32);
    ea1 += __shfl_xor(ea1, 32);
    if (lane < 32) {
        atomicAdd(&rowsum[rbase + lm], ea0);
        atomicAdd(&rowsum[rbase + 32 + lm], ea1);
    }
}

// ---------------- Kernel 3: finalize ----------------------------------------
__global__ __launch_bounds__(256) void nt_finalize(
    const float* __restrict__ rowsum, const float* __restrict__ posPartial,
    float* __restrict__ out)
{
    const int tid = threadIdx.x;
    float acc = 0.f;
#pragma unroll
    for (int it = 0; it < NN / 256; ++it)
        acc += __builtin_amdgcn_logf(rowsum[tid + it * 256]);   // log2
    float pacc = 0.f;
#pragma unroll
    for (int it = 0; it < 4; ++it)
        pacc += posPartial[tid + it * 256];

#pragma unroll
    for (int off = 32; off > 0; off >>= 1) {
        acc  += __shfl_xor(acc,  off);
        pacc += __shfl_xor(pacc, off);
    }
    __shared__ float sa[4], sp[4];
    const int wave = tid >> 6;
    if ((tid & 63) == 0) { sa[wave] = acc; sp[wave] = pacc; }
    __syncthreads();
    if (tid == 0) {
        const float lntot = (sa[0] + sa[1] + sa[2] + sa[3]) * 0.6931471805599453f;
        const float ptot  = sp[0] + sp[1] + sp[2] + sp[3];
        out[0] = (lntot - 4.0f * ptot) * (1.0f / (float)NN);
    }
}

// ---------------- Launch ------------------------------------------------------
extern "C" void kernel_launch(void* const* d_in, const int* in_sizes, int n_in,
                              void* d_out, int out_size, void* d_ws, size_t ws_size,
                              hipStream_t stream) {
    const float* zi = (const float*)d_in[0];
    const float* zj = (const float*)d_in[1];
    float* out = (float*)d_out;

    _Float16* Z = (_Float16*)d_ws;                                  // 4 MB
    float* rowsum = (float*)((char*)d_ws + (size_t)NN * DD * 2);    // 32 KB
    float* posPartial = rowsum + NN;                                // 4 KB

    nt_normalize<<<BB / 4, 256, 0, stream>>>(zi, zj, Z, posPartial, rowsum);
    nt_simexp<<<NRT * NCH, 256, 0, stream>>>((const _Float16*)Z, rowsum);
    nt_finalize<<<1, 256, 0, stream>>>(rowsum, posPartial, out);
}

// Round 7
// 105.650 us; speedup vs baseline: 1.6881x; 1.0466x over previous
//
#include <hip/hip_runtime.h>
#include <hip/hip_bf16.h>

// NT-Xent (SimCLR) loss, B=4096, D=256, N=8192, T=0.5.
// loss = [ sum_i log(sum_{j!=i} exp(sim_ij * 2)) - 4 * sum_{i<B} pos_i ] / N
//
// Z pre-scaled by sqrt(2*log2 e) so MFMA emits sim*2*log2e (epilogue = bare
// exp2); pos uses the exact fp32 path.
//
// SYMMETRY: sim = sim^T, so only the upper triangle of 256x256 block-tiles is
// computed: 528 blocks for pairs (i<=j). Off-diagonal tiles contribute
//   - col-sums (ea path, per-lane, as before)      -> rowsum[i-block rows]
//   - row-sums (butterfly + LDS accumulator, new)  -> rowsum[j-block rows]
// Diagonal tiles use only the (self-masked) ea path -- the full tile covers
// every column once, so adding the row path would double count.
//
// R5/R6 lessons kept: launch_bounds(256,2) for bfrag residency (VGPR_Count
// must stay ~200+, FETCH ~20MB; 128/64 means demotion), R4's per-tile order
// (barrier, load-next, kloop, epilogue, store-next), single accumulator set.

constexpr int BB = 4096;     // batch
constexpr int NN = 8192;     // 2*batch
constexpr int DD = 256;      // feature dim
constexpr int RT = 256;      // rows per block side
constexpr int NBT = NN / RT; // 32 block-tiles per side
constexpr int NBLK = NBT * (NBT + 1) / 2;  // 528 triangle blocks
constexpr int CSTEPS = RT / 32;            // 8 c-tiles of 32 rows

typedef _Float16 half4v __attribute__((ext_vector_type(4)));
typedef _Float16 half8v __attribute__((ext_vector_type(8)));
typedef float floatx16 __attribute__((ext_vector_type(16)));

// sqrt(2*log2(e)) : each side of the dot product carries one factor.
#define SQK 1.69864414f

// ---------------- Kernel 1: normalize rows -> f16 (pre-scaled), pos, zero ----
__global__ __launch_bounds__(256) void nt_normalize(
    const float* __restrict__ zi, const float* __restrict__ zj,
    _Float16* __restrict__ Z, float* __restrict__ posPartial,
    float* __restrict__ rowsum)
{
    const int lane = threadIdx.x & 63;
    const int wave = threadIdx.x >> 6;
    const int i = blockIdx.x * 4 + wave;   // pair index, < BB

    // Zero rowsum (8192 floats); stream-ordered before simexp, so no race.
    if (blockIdx.x < 32) rowsum[blockIdx.x * 256 + threadIdx.x] = 0.f;

    const float4 a = ((const float4*)(zi + (size_t)i * DD))[lane];
    const float4 b = ((const float4*)(zj + (size_t)i * DD))[lane];

    float ssi = a.x*a.x + a.y*a.y + a.z*a.z + a.w*a.w;
    float ssj = b.x*b.x + b.y*b.y + b.z*b.z + b.w*b.w;
    float dd  = a.x*b.x + a.y*b.y + a.z*b.z + a.w*b.w;
#pragma unroll
    for (int off = 32; off > 0; off >>= 1) {
        ssi += __shfl_xor(ssi, off);
        ssj += __shfl_xor(ssj, off);
        dd  += __shfl_xor(dd,  off);
    }
    const float invi = rsqrtf(ssi) * SQK;   // fold sqrt(2*log2e) into each side
    const float invj = rsqrtf(ssj) * SQK;

    half4v ha, hb;
    ha.x = (_Float16)(a.x * invi); ha.y = (_Float16)(a.y * invi);
    ha.z = (_Float16)(a.z * invi); ha.w = (_Float16)(a.w * invi);
    hb.x = (_Float16)(b.x * invj); hb.y = (_Float16)(b.y * invj);
    hb.z = (_Float16)(b.z * invj); hb.w = (_Float16)(b.w * invj);

    ((half4v*)(Z + (size_t)i * DD))[lane]        = ha;
    ((half4v*)(Z + (size_t)(BB + i) * DD))[lane] = hb;

    __shared__ float ps[4];
    if (lane == 0) ps[wave] = dd * invi * invj * (1.0f / (SQK * SQK)); // exact pos
    __syncthreads();
    if (threadIdx.x == 0)
        posPartial[blockIdx.x] = ps[0] + ps[1] + ps[2] + ps[3];
}

// ---------------- Kernel 2: triangular fused sim-GEMM + exp + row-sum --------
// Grid: 528 blocks (pairs i<=j), 256 threads (4 waves). Wave owns 64 i-rows
// (B-fragments resident in registers, whole K=256). The j-block's 256 rows
// staged 32 at a time into double-buffered swizzled LDS (A-fragments).
__global__ __launch_bounds__(256, 2) void nt_simexp(
    const _Float16* __restrict__ Z, float* __restrict__ rowsum)
{
    __shared__ _Float16 lds[2][32 * DD];   // 2 x 16 KB, 16B-granule swizzled
    __shared__ float rowacc[RT];           // j-block row-sum accumulator (1 KB)

    // Decode triangle pair: t = j(j+1)/2 + i, i <= j.
    const int t = blockIdx.x;
    int j = (int)((sqrtf(8.0f * (float)t + 1.0f) - 1.0f) * 0.5f);
    while ((j + 1) * (j + 2) / 2 <= t) ++j;
    while (j * (j + 1) / 2 > t) --j;
    const int i = t - ((j * (j + 1)) >> 1);
    const bool blockdiag = (i == j);

    const int tid = threadIdx.x;
    const int wave = tid >> 6;
    const int lane = tid & 63;
    const int lm = lane & 31;           // MFMA row/col index within 32
    const int lh = lane >> 5;           // half select

    const int rbase = i * RT + wave * 64;  // this wave's 64 i-rows (output cols)
    const int cchunk = j * RT;             // j-block rows (output rows)

    // B fragments: lane holds col n = lm, k = lh*8 + jj, 16 k-steps.
    half8v bfrag[2][16];
#pragma unroll
    for (int b = 0; b < 2; ++b) {
        const _Float16* rowp = Z + (size_t)(rbase + b * 32 + lm) * DD + lh * 8;
#pragma unroll
        for (int s = 0; s < 16; ++s)
            bfrag[b][s] = *(const half8v*)(rowp + s * 16);
    }

    // Staging granule coords (4 granules of 16B per thread per tile).
    const int g_c0 = tid >> 5;          // c row for it=0
    const int g_kc = tid & 31;

    half8v pre[4];
    auto loadTile = [&](int cs) {
#pragma unroll
        for (int it = 0; it < 4; ++it) {
            const int c = g_c0 + it * 8;
            pre[it] = *(const half8v*)(Z + (size_t)(cchunk + cs * 32 + c) * DD + g_kc * 8);
        }
    };
    auto storeTile = [&](int buf) {
#pragma unroll
        for (int it = 0; it < 4; ++it) {
            const int c = g_c0 + it * 8;
            *(half8v*)(&lds[buf][c * DD + (g_kc ^ (c & 7)) * 8]) = pre[it];
        }
    };

    float ea0 = 0.f, ea1 = 0.f, eb0 = 0.f, eb1 = 0.f;

    // Prologue: zero rowacc, stage tile 0.
    rowacc[tid] = 0.f;
    loadTile(0);
    storeTile(0);

    for (int cs = 0; cs < CSTEPS; ++cs) {
        const int cbase = cchunk + cs * 32;

        __syncthreads();                      // lds[cs&1] (and rowacc) ready
        if (cs + 1 < CSTEPS) loadTile(cs + 1);

        floatx16 c0, c1;
#pragma unroll
        for (int r = 0; r < 16; ++r) { c0[r] = 0.f; c1[r] = 0.f; }

        const _Float16* abuf = lds[cs & 1];
#pragma unroll
        for (int s = 0; s < 16; ++s) {
            // A fragment: lane = j-row lm, k = lh*8 + jj; logical granule 2s+lh.
            const int phys = (2 * s + lh) ^ (lm & 7);
            half8v af = *(const half8v*)(&abuf[lm * DD + phys * 8]);
            c0 = __builtin_amdgcn_mfma_f32_32x32x16_f16(af, bfrag[0][s], c0, 0, 0, 0);
            c1 = __builtin_amdgcn_mfma_f32_32x32x16_f16(af, bfrag[1][s], c1, 0, 0, 0);
        }

        // c0[r] (lane lm,lh) = scaled sim( j-row cbase+mrow(r,lh),
        //                                  i-col rbase+lm [+32 for c1] ).
        if (!blockdiag) {
            // ea: col-sums -> rowsum[i-rows]; v: row-sums -> rowacc[j-rows].
            float v[16];
#pragma unroll
            for (int r = 0; r < 16; ++r) {
                const float e0 = __builtin_amdgcn_exp2f(c0[r]);
                const float e1 = __builtin_amdgcn_exp2f(c1[r]);
                if (r & 1) { eb0 += e0; eb1 += e1; }
                else       { ea0 += e0; ea1 += e1; }
                v[r] = e0 + e1;               // same j-row, two i-cols
            }
            // Butterfly over the 32 lanes of this half (sum over i-cols).
#pragma unroll
            for (int off = 1; off <= 16; off <<= 1)
#pragma unroll
                for (int r = 0; r < 16; ++r)
                    v[r] += __shfl_xor(v[r], off);
            if (lm == 0) {
#pragma unroll
                for (int r = 0; r < 16; ++r) {
                    const int mrow = (r & 3) + 8 * (r >> 2) + 4 * lh;
                    atomicAdd(&rowacc[cs * 32 + mrow], v[r]);
                }
            }
        } else {
            // Diagonal block: masked ea path only (covers every column once).
#pragma unroll
            for (int r = 0; r < 16; ++r) {
                const int mrow = (r & 3) + 8 * (r >> 2) + 4 * lh;
                float e0 = __builtin_amdgcn_exp2f(c0[r]);
                float e1 = __builtin_amdgcn_exp2f(c1[r]);
                if ((cbase == rbase)      && (mrow == lm)) e0 = 0.f;
                if ((cbase == rbase + 32) && (mrow == lm)) e1 = 0.f;
                if (r & 1) { eb0 += e0; eb1 += e1; }
                else       { ea0 += e0; ea1 += e1; }
            }
        }

        if (cs + 1 < CSTEPS) storeTile((cs + 1) & 1);  // other buffer: no race
    }

    // Col-sum totals: combine the two lane-halves (sum over all 256 j-rows).
    ea0 += eb0; ea1 += eb1;
    ea0 += __shfl_xor(ea0, 32);
    ea1 += __shfl_xor(ea1, 32);
    if (lane < 32) {
        atomicAdd(&rowsum[rbase + lm], ea0);
        atomicAdd(&rowsum[rbase + 32 + lm], ea1);
    }

    // Row-sum flush for off-diagonal blocks.
    __syncthreads();
    if (!blockdiag) atomicAdd(&rowsum[cchunk + tid], rowacc[tid]);
}

// ---------------- Kernel 3: finalize ----------------------------------------
__global__ __launch_bounds__(256) void nt_finalize(
    const float* __restrict__ rowsum, const float* __restrict__ posPartial,
    float* __restrict__ out)
{
    const int tid = threadIdx.x;
    float acc = 0.f;
#pragma unroll
    for (int it = 0; it < NN / 256; ++it)
        acc += __builtin_amdgcn_logf(rowsum[tid + it * 256]);   // log2
    float pacc = 0.f;
#pragma unroll
    for (int it = 0; it < 4; ++it)
        pacc += posPartial[tid + it * 256];

#pragma unroll
    for (int off = 32; off > 0; off >>= 1) {
        acc  += __shfl_xor(acc,  off);
        pacc += __shfl_xor(pacc, off);
    }
    __shared__ float sa[4], sp[4];
    const int wave = tid >> 6;
    if ((tid & 63) == 0) { sa[wave] = acc; sp[wave] = pacc; }
    __syncthreads();
    if (tid == 0) {
        const float lntot = (sa[0] + sa[1] + sa[2] + sa[3]) * 0.6931471805599453f;
        const float ptot  = sp[0] + sp[1] + sp[2] + sp[3];
        out[0] = (lntot - 4.0f * ptot) * (1.0f / (float)NN);
    }
}

// ---------------- Launch ------------------------------------------------------
extern "C" void kernel_launch(void* const* d_in, const int* in_sizes, int n_in,
                              void* d_out, int out_size, void* d_ws, size_t ws_size,
                              hipStream_t stream) {
    const float* zi = (const float*)d_in[0];
    const float* zj = (const float*)d_in[1];
    float* out = (float*)d_out;

    _Float16* Z = (_Float16*)d_ws;                                  // 4 MB
    float* rowsum = (float*)((char*)d_ws + (size_t)NN * DD * 2);    // 32 KB
    float* posPartial = rowsum + NN;                                // 4 KB

    nt_normalize<<<BB / 4, 256, 0, stream>>>(zi, zj, Z, posPartial, rowsum);
    nt_simexp<<<NBLK, 256, 0, stream>>>((const _Float16*)Z, rowsum);
    nt_finalize<<<1, 256, 0, stream>>>(rowsum, posPartial, out);
}